// Round 10
// baseline (571.368 us; speedup 1.0000x reference)
//
#include <hip/hip_runtime.h>
#include <hip/hip_bf16.h>
#include <stdint.h>

#define HIDDEN 2048
#define SEQ 4096
#define NH 8
#define HD 256

typedef float f32x4 __attribute__((ext_vector_type(4)));
typedef short s16x8 __attribute__((ext_vector_type(8)));
typedef float f32x4v __attribute__((ext_vector_type(4)));
typedef unsigned int u32x2 __attribute__((ext_vector_type(2)));

// scale folded into Q at projection: (1/sqrt(256)) * log2(e)
#define QSCALE 0.09016844005556021f

__device__ inline uint16_t f2bf(float f) {
  union { float f; uint32_t u; } v;
  v.f = f;
  uint32_t r = (v.u + 0x7fffu + ((v.u >> 16) & 1u)) >> 16;
  return (uint16_t)r;
}

// two f32 -> packed 2x bf16 in one u32 (lo = a, hi = b)
__device__ inline uint32_t cvtpk(float a, float b) {
  uint32_t r;
  asm("v_cvt_pk_bf16_f32 %0, %1, %2" : "=v"(r) : "v"(a), "v"(b));
  return r;
}

__device__ inline void gll16(const uint16_t* src, uint16_t* lds) {
  // async global->LDS, 16B per lane; LDS dst is wave-uniform base + lane*16
  __builtin_amdgcn_global_load_lds(
      (const __attribute__((address_space(1))) unsigned int*)src,
      (__attribute__((address_space(3))) unsigned int*)lds, 16, 0, 0);
}

// ---------------- cast x (fp32 -> bf16) ----------------
__global__ __launch_bounds__(256) void cast_kernel(const float* __restrict__ in,
                                                   uint16_t* __restrict__ out, int n4) {
  int i = blockIdx.x * 256 + threadIdx.x;
  if (i >= n4) return;
  f32x4v v = ((const f32x4v*)in)[i];
  union { uint16_t u[4]; uint64_t l; } o;
  o.u[0] = f2bf(v.x); o.u[1] = f2bf(v.y); o.u[2] = f2bf(v.z); o.u[3] = f2bf(v.w);
  ((uint64_t*)out)[i] = o.l;
}

// ---------------- transpose + cast: in[R][C] fp32 -> out[C][R] bf16 ----------------
__global__ __launch_bounds__(256) void transpose_cast_kernel(const float* __restrict__ in,
                                                             uint16_t* __restrict__ out,
                                                             int R, int C) {
  __shared__ uint16_t tile[64][65];
  int t = threadIdx.x;
  int ctiles = C >> 6;
  int c0 = (blockIdx.x % ctiles) << 6;
  int r0 = (blockIdx.x / ctiles) << 6;
#pragma unroll
  for (int p = 0; p < 16; ++p) {
    int r = p * 4 + (t >> 6), c = t & 63;
    tile[c][r] = f2bf(in[(size_t)(r0 + r) * C + c0 + c]);
  }
  __syncthreads();
#pragma unroll
  for (int p = 0; p < 16; ++p) {
    int r = p * 4 + (t >> 6), c = t & 63;
    out[(size_t)(c0 + r) * R + r0 + c] = tile[r][c];
  }
}

// ---------------- GEMM core: C[128x128] = A[M][K] * BT[N][K]^T ----------------
// 256 threads, 4 waves (2x2 of 64x64), BK=32, 16x16x32 bf16 MFMA.
// 2-phase double-buffered staging: one barrier per K-step.
__device__ inline void gemm_tile_core(const uint16_t* __restrict__ A,
                                      const uint16_t* __restrict__ BT, int K, int m0,
                                      uint16_t* Alds, uint16_t* Blds, f32x4 acc[4][4]) {
  const int t = threadIdx.x, lane = t & 63, wid = t >> 6;
  const int l15 = lane & 15, l4 = lane >> 4;
  const int wm = wid >> 1, wn = wid & 1;
#pragma unroll
  for (int i = 0; i < 4; ++i)
#pragma unroll
    for (int j = 0; j < 4; ++j) acc[i][j] = f32x4{0.f, 0.f, 0.f, 0.f};

  auto stage = [&](int kt, int b) {
#pragma unroll
    for (int i = 0; i < 2; ++i) {
      int j = i * 256 + t;
      gll16(A + (size_t)(m0 + (j >> 2)) * K + kt + (j & 3) * 8,
            Alds + b * 4096 + (i * 256 + wid * 64) * 8);
    }
#pragma unroll
    for (int i = 0; i < 2; ++i) {
      int j = i * 256 + t;
      gll16(BT + (size_t)(j >> 2) * K + kt + (j & 3) * 8,
            Blds + b * 4096 + (i * 256 + wid * 64) * 8);
    }
  };

  stage(0, 0);
  int b = 0;
  for (int kt = 0; kt < K; kt += 32, b ^= 1) {
    __syncthreads();  // drains stage(kt); all waves done reading buf b^1
    if (kt + 32 < K) stage(kt + 32, b ^ 1);
    s16x8 av[4], bv[4];
#pragma unroll
    for (int mi = 0; mi < 4; ++mi)
      av[mi] = *(const s16x8*)(Alds + b * 4096 + (wm * 64 + mi * 16 + l15) * 32 + l4 * 8);
#pragma unroll
    for (int nj = 0; nj < 4; ++nj)
      bv[nj] = *(const s16x8*)(Blds + b * 4096 + (wn * 64 + nj * 16 + l15) * 32 + l4 * 8);
#pragma unroll
    for (int mi = 0; mi < 4; ++mi)
#pragma unroll
      for (int nj = 0; nj < 4; ++nj)
        acc[mi][nj] = __builtin_amdgcn_mfma_f32_16x16x32_bf16(av[mi], bv[nj],
                                                              acc[mi][nj], 0, 0, 0);
  }
}

// ---------------- K1: QKV projection ----------------
__global__ __launch_bounds__(256) void gemm_qkv_kernel(
    const uint16_t* __restrict__ xb, const uint16_t* __restrict__ wqT,
    const uint16_t* __restrict__ wkvT, const float* __restrict__ bq,
    const float* __restrict__ bkv, uint16_t* __restrict__ Qws,
    uint16_t* __restrict__ Kws, uint16_t* __restrict__ VTws) {
  __shared__ uint16_t Alds[8192], Blds[8192];
  // bijective XCD swizzle: grid 576 = 8 * 72
  int b0 = blockIdx.x;
  int bid = (b0 & 7) * 72 + (b0 >> 3);
  int bn = bid % 18, bm = bid / 18;
  int m0 = bm * 128;
  const uint16_t* BT = (bn < 16) ? (wqT + (size_t)bn * 128 * HIDDEN)
                                 : (wkvT + (size_t)(bn - 16) * 128 * HIDDEN);
  f32x4 acc[4][4];
  gemm_tile_core(xb, BT, HIDDEN, m0, Alds, Blds, acc);
  const int lane = threadIdx.x & 63, wid = threadIdx.x >> 6;
  const int l15 = lane & 15, l4 = lane >> 4;
  const int wm = wid >> 1, wn = wid & 1;
#pragma unroll
  for (int mi = 0; mi < 4; ++mi) {
#pragma unroll
    for (int nj = 0; nj < 4; ++nj) {
      int nloc = bn * 128 + wn * 64 + nj * 16 + l15;
#pragma unroll
      for (int r = 0; r < 4; ++r) {
        int m = m0 + wm * 64 + mi * 16 + 4 * l4 + r;
        float v = acc[mi][nj][r];
        if (bn < 16) {
          v = (v + bq[nloc]) * QSCALE;  // fold softmax scale*log2e into Q
          uint16_t b = f2bf(v);
          int head = nloc >> 8, d = nloc & 255;
          Qws[((size_t)head * SEQ + m) * HD + d] = b;
        } else {
          int d = nloc - 2048;
          v += bkv[d];
          uint16_t b = f2bf(v);
          Kws[(size_t)m * HD + d] = b;
          VTws[(size_t)d * SEQ + m] = b;
        }
      }
    }
  }
}

// ---------------- K2: flash attention ----------------
// 256 blocks: h = bid&7, p = bid>>3 (0..31). Block processes q-tiles (63-p)
// then (p): exactly 65 kv-tiles of work each -> in-block causal balance
// (measured-good in round 1; do NOT rely on dispatch pairing - round 7 lesson).
// K staged in double-buffered LDS (XOR-swizzled); V fragments loaded DIRECTLY
// from global VTws (L2-resident, 2MB) into registers -> no VT staging, no VT
// LDS reads: ~45% less LDS traffic per tile.
__global__ __launch_bounds__(256) void attn_kernel(const uint16_t* __restrict__ Qws,
                                                   const uint16_t* __restrict__ Kws,
                                                   const uint16_t* __restrict__ VTws,
                                                   uint16_t* __restrict__ Ows) {
  __shared__ unsigned char smem[74752];  // K dbuf 2x32KB | Pw 4x2304B
  const int t = threadIdx.x, lane = t & 63, wid = t >> 6;
  const int l15 = lane & 15, l4 = lane >> 4;
  const int h = blockIdx.x & 7, p = blockIdx.x >> 3;
  uint16_t* Pw = (uint16_t*)(smem + 65536 + wid * 2304);  // [16][72] bf16 per wave

  // hoisted swizzled K LDS read byte-offsets (kvt-independent: row&7 == l15&7)
  int koff[8];
#pragma unroll
  for (int kk = 0; kk < 8; ++kk) {
    int c = kk * 4 + l4;
    int cs = (c & ~7) | ((c ^ l15) & 7);
    koff[kk] = l15 * 512 + cs * 16;  // + kvt*8192 + buf*32768
  }

  auto stageK = [&](int kb, int buf) {
    uint16_t* Klds = (uint16_t*)(smem + buf * 32768);
#pragma unroll
    for (int i = 0; i < 8; ++i) {
      int j = i * 256 + t;
      int r = j >> 5, cp = j & 31;
      int c = (cp & ~7) | ((cp ^ r) & 7);
      gll16(Kws + (size_t)(kb * 64 + r) * HD + c * 8, Klds + (i * 256 + wid * 64) * 8);
    }
  };

  for (int half = 0; half < 2; ++half) {
    const int qb = half ? p : 63 - p;
    const int qrow = qb * 64 + wid * 16 + l15;  // this lane's softmax row (q)

    // Q fragments (B-operand of swapped QK^T), scale pre-folded
    s16x8 qf[8];
    const uint16_t* qbase = Qws + ((size_t)h * SEQ + qrow) * HD;
#pragma unroll
    for (int kk = 0; kk < 8; ++kk) qf[kk] = *(const s16x8*)(qbase + kk * 32 + l4 * 8);

    float mrun = -1e30f, lrun = 0.f;
    f32x4 oacc[16];
#pragma unroll
    for (int i = 0; i < 16; ++i) oacc[i] = f32x4{0.f, 0.f, 0.f, 0.f};

    const int nt = qb + 1;
    __syncthreads();  // protect K buffers from previous half's readers
    stageK(0, 0);

    for (int kb = 0; kb < nt; ++kb) {
      const int buf = kb & 1;
      __syncthreads();  // stage(kb) landed (issued one full phase ago)
      if (kb + 1 < nt) stageK(kb + 1, buf ^ 1);

      // issue ALL V-fragment loads for this tile straight from global (L2-hit).
      // vf[dt*2+kk] = VT[d=dt*16+l15][kb*64 + (kk*4+l4)*8 .. +8] -> PV B-frag.
      s16x8 vf[32];
#pragma unroll
      for (int dt = 0; dt < 16; ++dt) {
#pragma unroll
        for (int kk = 0; kk < 2; ++kk) {
          vf[dt * 2 + kk] = *(const s16x8*)(VTws + (size_t)(dt * 16 + l15) * SEQ +
                                            kb * 64 + (kk * 4 + l4) * 8);
        }
      }

      const unsigned char* Klds = (const unsigned char*)(smem + buf * 32768);
      // swapped QK^T: S^T = K * Q^T ; acc: row=kv_sub=4*l4+r, col=q=l15
      f32x4 sacc[4];
#pragma unroll
      for (int i = 0; i < 4; ++i) sacc[i] = f32x4{0.f, 0.f, 0.f, 0.f};
#pragma unroll
      for (int kvt = 0; kvt < 4; ++kvt) {
#pragma unroll
        for (int kk = 0; kk < 8; ++kk) {
          s16x8 kf = *(const s16x8*)(Klds + kvt * 8192 + koff[kk]);
          sacc[kvt] = __builtin_amdgcn_mfma_f32_16x16x32_bf16(kf, qf[kk], sacc[kvt], 0, 0, 0);
        }
      }

      // online softmax in log2 domain (scale pre-folded into Q)
      float pv[16];
      float vmax = -1e30f;
      const bool diag = (kb == qb);
#pragma unroll
      for (int kvt = 0; kvt < 4; ++kvt) {
#pragma unroll
        for (int r = 0; r < 4; ++r) {
          float s = sacc[kvt][r];
          if (diag) {
            int kv = kb * 64 + kvt * 16 + 4 * l4 + r;
            if (kv > qrow) s = -1e30f;
          }
          pv[kvt * 4 + r] = s;
          vmax = fmaxf(vmax, s);
        }
      }
      vmax = fmaxf(vmax, __shfl_xor(vmax, 16));
      vmax = fmaxf(vmax, __shfl_xor(vmax, 32));

      // defer-max: skip O-rescale unless some row's max grew by > 8 (P <= 2^8)
      if (!__all(vmax - mrun <= 8.0f)) {
        float mnew = fmaxf(mrun, vmax);
        float alpha = exp2f(mrun - mnew);
        float a4[4];
#pragma unroll
        for (int r = 0; r < 4; ++r) a4[r] = __shfl(alpha, 4 * l4 + r);
#pragma unroll
        for (int dt = 0; dt < 16; ++dt) {
#pragma unroll
          for (int r = 0; r < 4; ++r) oacc[dt][r] *= a4[r];
        }
        lrun *= alpha;
        mrun = mnew;
      }
      float rsum = 0.f;
#pragma unroll
      for (int i = 0; i < 16; ++i) {
        float pe = exp2f(pv[i] - mrun);
        pv[i] = pe;
        rsum += pe;
      }
      rsum += __shfl_xor(rsum, 16);
      rsum += __shfl_xor(rsum, 32);
      lrun += rsum;

      // store P to per-wave LDS: P[q=l15][kv], cvt_pk packed (2 f32 -> u32)
#pragma unroll
      for (int kvt = 0; kvt < 4; ++kvt) {
        u32x2 w;
        w.x = cvtpk(pv[kvt * 4 + 0], pv[kvt * 4 + 1]);
        w.y = cvtpk(pv[kvt * 4 + 2], pv[kvt * 4 + 3]);
        *(u32x2*)(Pw + l15 * 72 + kvt * 16 + l4 * 4) = w;
      }
      // PV: O[q][d] += P * V   (A=P from Pw, B=V from registers)
      s16x8 pa[2];
#pragma unroll
      for (int kk = 0; kk < 2; ++kk)
        pa[kk] = *(const s16x8*)(Pw + l15 * 72 + kk * 32 + l4 * 8);
#pragma unroll
      for (int dt = 0; dt < 16; ++dt) {
#pragma unroll
        for (int kk = 0; kk < 2; ++kk)
          oacc[dt] = __builtin_amdgcn_mfma_f32_16x16x32_bf16(pa[kk], vf[dt * 2 + kk],
                                                             oacc[dt], 0, 0, 0);
      }
    }

    // epilogue: O /= l, write bf16 to Ows[s][h*256+d]
    float linv = 1.0f / lrun;
    float li4[4];
#pragma unroll
    for (int r = 0; r < 4; ++r) li4[r] = __shfl(linv, 4 * l4 + r);
#pragma unroll
    for (int dt = 0; dt < 16; ++dt) {
#pragma unroll
      for (int r = 0; r < 4; ++r) {
        int s = qb * 64 + wid * 16 + 4 * l4 + r;
        int col = h * HD + dt * 16 + l15;
        Ows[(size_t)s * HIDDEN + col] = f2bf(oacc[dt][r] * li4[r]);
      }
    }
  }
}

// ---------------- K3: output projection (fp32 out + bias) ----------------
__global__ __launch_bounds__(256) void gemm_out_kernel(const uint16_t* __restrict__ Ows,
                                                       const uint16_t* __restrict__ woT,
                                                       const float* __restrict__ bo,
                                                       float* __restrict__ Y) {
  __shared__ uint16_t Alds[8192], Blds[8192];
  // bijective XCD swizzle: grid 512 = 8 * 64
  int b0 = blockIdx.x;
  int bid = (b0 & 7) * 64 + (b0 >> 3);
  int bn = bid % 16, bm = bid / 16;
  int m0 = bm * 128;
  f32x4 acc[4][4];
  gemm_tile_core(Ows, woT + (size_t)bn * 128 * HIDDEN, HIDDEN, m0, Alds, Blds, acc);
  const int lane = threadIdx.x & 63, wid = threadIdx.x >> 6;
  const int l15 = lane & 15, l4 = lane >> 4;
  const int wm = wid >> 1, wn = wid & 1;
#pragma unroll
  for (int mi = 0; mi < 4; ++mi) {
#pragma unroll
    for (int nj = 0; nj < 4; ++nj) {
      int n = bn * 128 + wn * 64 + nj * 16 + l15;
      float bias = bo[n];
#pragma unroll
      for (int r = 0; r < 4; ++r) {
        int m = m0 + wm * 64 + mi * 16 + 4 * l4 + r;
        Y[(size_t)m * HIDDEN + n] = acc[mi][nj][r] + bias;
      }
    }
  }
}

extern "C" void kernel_launch(void* const* d_in, const int* in_sizes, int n_in,
                              void* d_out, int out_size, void* d_ws, size_t ws_size,
                              hipStream_t stream) {
  const float* x = (const float*)d_in[0];
  const float* wq = (const float*)d_in[1];
  const float* bq = (const float*)d_in[2];
  const float* wkv = (const float*)d_in[3];
  const float* bkv = (const float*)d_in[4];
  const float* wo = (const float*)d_in[5];
  const float* bo = (const float*)d_in[6];
  float* Y = (float*)d_out;

  uint8_t* ws = (uint8_t*)d_ws;
  uint16_t* xb   = (uint16_t*)(ws + 0);          // 16 MB  x as bf16 [4096][2048]
  uint16_t* wqT  = (uint16_t*)(ws + 16777216);   // 8 MB   [2048 n][2048 k]
  uint16_t* wkvT = (uint16_t*)(ws + 25165824);   // 1 MB   [256 n][2048 k]
  uint16_t* woT  = (uint16_t*)(ws + 26214400);   // 8 MB   [2048 n][2048 k]
  uint16_t* Qws  = (uint16_t*)(ws + 34603008);   // 16 MB  [8][4096][256]
  uint16_t* Kws  = (uint16_t*)(ws + 51380224);   // 2 MB   [4096][256]
  uint16_t* VTws = (uint16_t*)(ws + 53477376);   // 2 MB   [256][4096]
  uint16_t* Ows  = (uint16_t*)(ws + 55574528);   // 16 MB  [4096][2048]

  // prep
  cast_kernel<<<8192, 256, 0, stream>>>(x, xb, (SEQ * HIDDEN) / 4);
  transpose_cast_kernel<<<1024, 256, 0, stream>>>(wq, wqT, HIDDEN, 2048);
  transpose_cast_kernel<<<128, 256, 0, stream>>>(wkv, wkvT, HIDDEN, 256);
  transpose_cast_kernel<<<1024, 256, 0, stream>>>(wo, woT, 2048, HIDDEN);
  // QKV projection
  gemm_qkv_kernel<<<32 * 18, 256, 0, stream>>>(xb, wqT, wkvT, bq, bkv, Qws, Kws, VTws);
  // attention (256 balanced blocks, in-block pairing)
  attn_kernel<<<256, 256, 0, stream>>>(Qws, Kws, VTws, Ows);
  // output projection
  gemm_out_kernel<<<32 * 16, 256, 0, stream>>>(Ows, woT, bo, Y);
}

// Round 11
// 436.663 us; speedup vs baseline: 1.3085x; 1.3085x over previous
//
#include <hip/hip_runtime.h>
#include <hip/hip_bf16.h>
#include <stdint.h>

#define HIDDEN 2048
#define SEQ 4096
#define NH 8
#define HD 256

typedef float f32x4 __attribute__((ext_vector_type(4)));
typedef short s16x8 __attribute__((ext_vector_type(8)));
typedef float f32x4v __attribute__((ext_vector_type(4)));
typedef unsigned int u32x2 __attribute__((ext_vector_type(2)));

// scale folded into Q at projection: (1/sqrt(256)) * log2(e)
#define QSCALE 0.09016844005556021f

__device__ inline uint16_t f2bf(float f) {
  union { float f; uint32_t u; } v;
  v.f = f;
  uint32_t r = (v.u + 0x7fffu + ((v.u >> 16) & 1u)) >> 16;
  return (uint16_t)r;
}

// two f32 -> packed 2x bf16 in one u32 (lo = a, hi = b)
__device__ inline uint32_t cvtpk(float a, float b) {
  uint32_t r;
  asm("v_cvt_pk_bf16_f32 %0, %1, %2" : "=v"(r) : "v"(a), "v"(b));
  return r;
}

__device__ inline void gll16(const uint16_t* src, uint16_t* lds) {
  // async global->LDS, 16B per lane; LDS dst is wave-uniform base + lane*16
  __builtin_amdgcn_global_load_lds(
      (const __attribute__((address_space(1))) unsigned int*)src,
      (__attribute__((address_space(3))) unsigned int*)lds, 16, 0, 0);
}

// ---------------- cast x (fp32 -> bf16) ----------------
__global__ __launch_bounds__(256) void cast_kernel(const float* __restrict__ in,
                                                   uint16_t* __restrict__ out, int n4) {
  int i = blockIdx.x * 256 + threadIdx.x;
  if (i >= n4) return;
  f32x4v v = ((const f32x4v*)in)[i];
  union { uint16_t u[4]; uint64_t l; } o;
  o.u[0] = f2bf(v.x); o.u[1] = f2bf(v.y); o.u[2] = f2bf(v.z); o.u[3] = f2bf(v.w);
  ((uint64_t*)out)[i] = o.l;
}

// ---------------- transpose + cast: in[R][C] fp32 -> out[C][R] bf16 ----------------
__global__ __launch_bounds__(256) void transpose_cast_kernel(const float* __restrict__ in,
                                                             uint16_t* __restrict__ out,
                                                             int R, int C) {
  __shared__ uint16_t tile[64][65];
  int t = threadIdx.x;
  int ctiles = C >> 6;
  int c0 = (blockIdx.x % ctiles) << 6;
  int r0 = (blockIdx.x / ctiles) << 6;
#pragma unroll
  for (int p = 0; p < 16; ++p) {
    int r = p * 4 + (t >> 6), c = t & 63;
    tile[c][r] = f2bf(in[(size_t)(r0 + r) * C + c0 + c]);
  }
  __syncthreads();
#pragma unroll
  for (int p = 0; p < 16; ++p) {
    int r = p * 4 + (t >> 6), c = t & 63;
    out[(size_t)(c0 + r) * R + r0 + c] = tile[r][c];
  }
}

// ---------------- GEMM core: C[128x128] = A[M][K] * BT[N][K]^T ----------------
// 256 threads, 4 waves (2x2 of 64x64), BK=32, 16x16x32 bf16 MFMA.
// 2-phase double-buffered staging: one barrier per K-step, prefetch in flight
// under MFMA.
__device__ inline void gemm_tile_core(const uint16_t* __restrict__ A,
                                      const uint16_t* __restrict__ BT, int K, int m0,
                                      uint16_t* Alds, uint16_t* Blds, f32x4 acc[4][4]) {
  const int t = threadIdx.x, lane = t & 63, wid = t >> 6;
  const int l15 = lane & 15, l4 = lane >> 4;
  const int wm = wid >> 1, wn = wid & 1;
#pragma unroll
  for (int i = 0; i < 4; ++i)
#pragma unroll
    for (int j = 0; j < 4; ++j) acc[i][j] = f32x4{0.f, 0.f, 0.f, 0.f};

  auto stage = [&](int kt, int b) {
#pragma unroll
    for (int i = 0; i < 2; ++i) {
      int j = i * 256 + t;
      gll16(A + (size_t)(m0 + (j >> 2)) * K + kt + (j & 3) * 8,
            Alds + b * 4096 + (i * 256 + wid * 64) * 8);
    }
#pragma unroll
    for (int i = 0; i < 2; ++i) {
      int j = i * 256 + t;
      gll16(BT + (size_t)(j >> 2) * K + kt + (j & 3) * 8,
            Blds + b * 4096 + (i * 256 + wid * 64) * 8);
    }
  };

  stage(0, 0);
  int b = 0;
  for (int kt = 0; kt < K; kt += 32, b ^= 1) {
    __syncthreads();  // drains stage(kt); all waves done reading buf b^1
    if (kt + 32 < K) stage(kt + 32, b ^ 1);
    s16x8 av[4], bv[4];
#pragma unroll
    for (int mi = 0; mi < 4; ++mi)
      av[mi] = *(const s16x8*)(Alds + b * 4096 + (wm * 64 + mi * 16 + l15) * 32 + l4 * 8);
#pragma unroll
    for (int nj = 0; nj < 4; ++nj)
      bv[nj] = *(const s16x8*)(Blds + b * 4096 + (wn * 64 + nj * 16 + l15) * 32 + l4 * 8);
#pragma unroll
    for (int mi = 0; mi < 4; ++mi)
#pragma unroll
      for (int nj = 0; nj < 4; ++nj)
        acc[mi][nj] = __builtin_amdgcn_mfma_f32_16x16x32_bf16(av[mi], bv[nj],
                                                              acc[mi][nj], 0, 0, 0);
  }
}

// ---------------- K1: QKV projection ----------------
__global__ __launch_bounds__(256) void gemm_qkv_kernel(
    const uint16_t* __restrict__ xb, const uint16_t* __restrict__ wqT,
    const uint16_t* __restrict__ wkvT, const float* __restrict__ bq,
    const float* __restrict__ bkv, uint16_t* __restrict__ Qws,
    uint16_t* __restrict__ Kws, uint16_t* __restrict__ VTws) {
  __shared__ uint16_t Alds[8192], Blds[8192];
  // bijective XCD swizzle: grid 576 = 8 * 72
  int b0 = blockIdx.x;
  int bid = (b0 & 7) * 72 + (b0 >> 3);
  int bn = bid % 18, bm = bid / 18;
  int m0 = bm * 128;
  const uint16_t* BT = (bn < 16) ? (wqT + (size_t)bn * 128 * HIDDEN)
                                 : (wkvT + (size_t)(bn - 16) * 128 * HIDDEN);
  f32x4 acc[4][4];
  gemm_tile_core(xb, BT, HIDDEN, m0, Alds, Blds, acc);
  const int lane = threadIdx.x & 63, wid = threadIdx.x >> 6;
  const int l15 = lane & 15, l4 = lane >> 4;
  const int wm = wid >> 1, wn = wid & 1;
#pragma unroll
  for (int mi = 0; mi < 4; ++mi) {
#pragma unroll
    for (int nj = 0; nj < 4; ++nj) {
      int nloc = bn * 128 + wn * 64 + nj * 16 + l15;
#pragma unroll
      for (int r = 0; r < 4; ++r) {
        int m = m0 + wm * 64 + mi * 16 + 4 * l4 + r;
        float v = acc[mi][nj][r];
        if (bn < 16) {
          v = (v + bq[nloc]) * QSCALE;  // fold softmax scale*log2e into Q
          uint16_t b = f2bf(v);
          int head = nloc >> 8, d = nloc & 255;
          Qws[((size_t)head * SEQ + m) * HD + d] = b;
        } else {
          int d = nloc - 2048;
          v += bkv[d];
          uint16_t b = f2bf(v);
          Kws[(size_t)m * HD + d] = b;
          VTws[(size_t)d * SEQ + m] = b;
        }
      }
    }
  }
}

// ---------------- K2: flash attention ----------------
// 256 blocks: h = bid&7, p = bid>>3 (0..31). Block processes q-tiles (63-p)
// then (p): exactly 65 kv-tiles per block -> in-block causal balance
// (measured 177.7us; pairing-by-dispatch and V-direct-global both measured
// worse - rounds 7/10). K AND VT staged in double-buffered XOR-swizzled LDS,
// one __syncthreads per kv-tile; cvt_pk P-packing; hoisted swizzled offsets.
__global__ __launch_bounds__(256) void attn_kernel(const uint16_t* __restrict__ Qws,
                                                   const uint16_t* __restrict__ Kws,
                                                   const uint16_t* __restrict__ VTws,
                                                   uint16_t* __restrict__ Ows) {
  __shared__ unsigned char smem[140288];  // K 2x32KB | VT 2x32KB | Pw 4x2304B
  const int t = threadIdx.x, lane = t & 63, wid = t >> 6;
  const int l15 = lane & 15, l4 = lane >> 4;
  const int h = blockIdx.x & 7, p = blockIdx.x >> 3;
  uint16_t* Pw = (uint16_t*)(smem + 131072 + wid * 2304);  // [16][72] bf16 per wave

  // hoisted swizzled LDS read byte-offsets (kvt/dt-independent: row&7 == l15&7)
  int koff[8];
#pragma unroll
  for (int kk = 0; kk < 8; ++kk) {
    int c = kk * 4 + l4;
    int cs = (c & ~7) | ((c ^ l15) & 7);
    koff[kk] = l15 * 512 + cs * 16;  // + kvt*8192
  }
  int voff[2];
#pragma unroll
  for (int kk = 0; kk < 2; ++kk) {
    int c = (kk * 4 + l4) ^ (l15 & 7);
    voff[kk] = l15 * 128 + c * 16;  // + dt*2048
  }

  auto stageKV = [&](int kb, int buf) {
    uint16_t* Klds = (uint16_t*)(smem + buf * 32768);
#pragma unroll
    for (int i = 0; i < 8; ++i) {
      int j = i * 256 + t;
      int r = j >> 5, cp = j & 31;
      int c = (cp & ~7) | ((cp ^ r) & 7);
      gll16(Kws + (size_t)(kb * 64 + r) * HD + c * 8, Klds + (i * 256 + wid * 64) * 8);
    }
    uint16_t* VTlds = (uint16_t*)(smem + 65536 + buf * 32768);
#pragma unroll
    for (int i = 0; i < 8; ++i) {
      int j = i * 256 + t;
      int d = j >> 3, cp = j & 7;
      int c = (cp ^ d) & 7;
      gll16(VTws + (size_t)d * SEQ + kb * 64 + c * 8, VTlds + (i * 256 + wid * 64) * 8);
    }
  };

  for (int half = 0; half < 2; ++half) {
    const int qb = half ? p : 63 - p;
    const int qrow = qb * 64 + wid * 16 + l15;  // this lane's softmax row (q)

    // Q fragments (B-operand of swapped QK^T), scale pre-folded
    s16x8 qf[8];
    const uint16_t* qbase = Qws + ((size_t)h * SEQ + qrow) * HD;
#pragma unroll
    for (int kk = 0; kk < 8; ++kk) qf[kk] = *(const s16x8*)(qbase + kk * 32 + l4 * 8);

    float mrun = -1e30f, lrun = 0.f;
    f32x4 oacc[16];
#pragma unroll
    for (int i = 0; i < 16; ++i) oacc[i] = f32x4{0.f, 0.f, 0.f, 0.f};

    const int nt = qb + 1;
    __syncthreads();  // protect buffers from previous half's readers
    stageKV(0, 0);

    for (int kb = 0; kb < nt; ++kb) {
      const int buf = kb & 1;
      __syncthreads();  // drains stage(kb) (issued one full phase ago)
      if (kb + 1 < nt) stageKV(kb + 1, buf ^ 1);
      const unsigned char* Klds = (const unsigned char*)(smem + buf * 32768);
      const unsigned char* VTlds = (const unsigned char*)(smem + 65536 + buf * 32768);

      // swapped QK^T: S^T = K * Q^T ; acc: row=kv_sub=4*l4+r, col=q=l15
      f32x4 sacc[4];
#pragma unroll
      for (int i = 0; i < 4; ++i) sacc[i] = f32x4{0.f, 0.f, 0.f, 0.f};
#pragma unroll
      for (int kvt = 0; kvt < 4; ++kvt) {
#pragma unroll
        for (int kk = 0; kk < 8; ++kk) {
          s16x8 kf = *(const s16x8*)(Klds + kvt * 8192 + koff[kk]);
          sacc[kvt] = __builtin_amdgcn_mfma_f32_16x16x32_bf16(kf, qf[kk], sacc[kvt], 0, 0, 0);
        }
      }

      // online softmax in log2 domain (scale pre-folded into Q)
      float pv[16];
      float vmax = -1e30f;
      const bool diag = (kb == qb);
#pragma unroll
      for (int kvt = 0; kvt < 4; ++kvt) {
#pragma unroll
        for (int r = 0; r < 4; ++r) {
          float s = sacc[kvt][r];
          if (diag) {
            int kv = kb * 64 + kvt * 16 + 4 * l4 + r;
            if (kv > qrow) s = -1e30f;
          }
          pv[kvt * 4 + r] = s;
          vmax = fmaxf(vmax, s);
        }
      }
      vmax = fmaxf(vmax, __shfl_xor(vmax, 16));
      vmax = fmaxf(vmax, __shfl_xor(vmax, 32));

      // defer-max: skip O-rescale unless some row's max grew by > 8 (P <= 2^8)
      if (!__all(vmax - mrun <= 8.0f)) {
        float mnew = fmaxf(mrun, vmax);
        float alpha = exp2f(mrun - mnew);
        float a4[4];
#pragma unroll
        for (int r = 0; r < 4; ++r) a4[r] = __shfl(alpha, 4 * l4 + r);
#pragma unroll
        for (int dt = 0; dt < 16; ++dt) {
#pragma unroll
          for (int r = 0; r < 4; ++r) oacc[dt][r] *= a4[r];
        }
        lrun *= alpha;
        mrun = mnew;
      }
      float rsum = 0.f;
#pragma unroll
      for (int i = 0; i < 16; ++i) {
        float pe = exp2f(pv[i] - mrun);
        pv[i] = pe;
        rsum += pe;
      }
      rsum += __shfl_xor(rsum, 16);
      rsum += __shfl_xor(rsum, 32);
      lrun += rsum;

      // store P to per-wave LDS: P[q=l15][kv], cvt_pk packed (2 f32 -> u32)
#pragma unroll
      for (int kvt = 0; kvt < 4; ++kvt) {
        u32x2 w;
        w.x = cvtpk(pv[kvt * 4 + 0], pv[kvt * 4 + 1]);
        w.y = cvtpk(pv[kvt * 4 + 2], pv[kvt * 4 + 3]);
        *(u32x2*)(Pw + l15 * 72 + kvt * 16 + l4 * 4) = w;
      }
      // PV: O[q][d] += P * V   (A=P from Pw, B=V from VTlds)
      s16x8 pa[2];
#pragma unroll
      for (int kk = 0; kk < 2; ++kk)
        pa[kk] = *(const s16x8*)(Pw + l15 * 72 + kk * 32 + l4 * 8);
#pragma unroll
      for (int dt = 0; dt < 16; ++dt) {
#pragma unroll
        for (int kk = 0; kk < 2; ++kk) {
          s16x8 vf = *(const s16x8*)(VTlds + dt * 2048 + voff[kk]);
          oacc[dt] = __builtin_amdgcn_mfma_f32_16x16x32_bf16(pa[kk], vf, oacc[dt], 0, 0, 0);
        }
      }
    }

    // epilogue: O /= l, write bf16 to Ows[s][h*256+d]
    float linv = 1.0f / lrun;
    float li4[4];
#pragma unroll
    for (int r = 0; r < 4; ++r) li4[r] = __shfl(linv, 4 * l4 + r);
#pragma unroll
    for (int dt = 0; dt < 16; ++dt) {
#pragma unroll
      for (int r = 0; r < 4; ++r) {
        int s = qb * 64 + wid * 16 + 4 * l4 + r;
        int col = h * HD + dt * 16 + l15;
        Ows[(size_t)s * HIDDEN + col] = f2bf(oacc[dt][r] * li4[r]);
      }
    }
  }
}

// ---------------- K3: output projection (fp32 out + bias) ----------------
__global__ __launch_bounds__(256) void gemm_out_kernel(const uint16_t* __restrict__ Ows,
                                                       const uint16_t* __restrict__ woT,
                                                       const float* __restrict__ bo,
                                                       float* __restrict__ Y) {
  __shared__ uint16_t Alds[8192], Blds[8192];
  // bijective XCD swizzle: grid 512 = 8 * 64
  int b0 = blockIdx.x;
  int bid = (b0 & 7) * 64 + (b0 >> 3);
  int bn = bid % 16, bm = bid / 16;
  int m0 = bm * 128;
  f32x4 acc[4][4];
  gemm_tile_core(Ows, woT + (size_t)bn * 128 * HIDDEN, HIDDEN, m0, Alds, Blds, acc);
  const int lane = threadIdx.x & 63, wid = threadIdx.x >> 6;
  const int l15 = lane & 15, l4 = lane >> 4;
  const int wm = wid >> 1, wn = wid & 1;
#pragma unroll
  for (int mi = 0; mi < 4; ++mi) {
#pragma unroll
    for (int nj = 0; nj < 4; ++nj) {
      int n = bn * 128 + wn * 64 + nj * 16 + l15;
      float bias = bo[n];
#pragma unroll
      for (int r = 0; r < 4; ++r) {
        int m = m0 + wm * 64 + mi * 16 + 4 * l4 + r;
        Y[(size_t)m * HIDDEN + n] = acc[mi][nj][r] + bias;
      }
    }
  }
}

extern "C" void kernel_launch(void* const* d_in, const int* in_sizes, int n_in,
                              void* d_out, int out_size, void* d_ws, size_t ws_size,
                              hipStream_t stream) {
  const float* x = (const float*)d_in[0];
  const float* wq = (const float*)d_in[1];
  const float* bq = (const float*)d_in[2];
  const float* wkv = (const float*)d_in[3];
  const float* bkv = (const float*)d_in[4];
  const float* wo = (const float*)d_in[5];
  const float* bo = (const float*)d_in[6];
  float* Y = (float*)d_out;

  uint8_t* ws = (uint8_t*)d_ws;
  uint16_t* xb   = (uint16_t*)(ws + 0);          // 16 MB  x as bf16 [4096][2048]
  uint16_t* wqT  = (uint16_t*)(ws + 16777216);   // 8 MB   [2048 n][2048 k]
  uint16_t* wkvT = (uint16_t*)(ws + 25165824);   // 1 MB   [256 n][2048 k]
  uint16_t* woT  = (uint16_t*)(ws + 26214400);   // 8 MB   [2048 n][2048 k]
  uint16_t* Qws  = (uint16_t*)(ws + 34603008);   // 16 MB  [8][4096][256]
  uint16_t* Kws  = (uint16_t*)(ws + 51380224);   // 2 MB   [4096][256]
  uint16_t* VTws = (uint16_t*)(ws + 53477376);   // 2 MB   [256][4096]
  uint16_t* Ows  = (uint16_t*)(ws + 55574528);   // 16 MB  [4096][2048]

  // prep
  cast_kernel<<<8192, 256, 0, stream>>>(x, xb, (SEQ * HIDDEN) / 4);
  transpose_cast_kernel<<<1024, 256, 0, stream>>>(wq, wqT, HIDDEN, 2048);
  transpose_cast_kernel<<<128, 256, 0, stream>>>(wkv, wkvT, HIDDEN, 256);
  transpose_cast_kernel<<<1024, 256, 0, stream>>>(wo, woT, 2048, HIDDEN);
  // QKV projection
  gemm_qkv_kernel<<<32 * 18, 256, 0, stream>>>(xb, wqT, wkvT, bq, bkv, Qws, Kws, VTws);
  // attention (256 balanced blocks, in-block pairing)
  attn_kernel<<<256, 256, 0, stream>>>(Qws, Kws, VTws, Ows);
  // output projection
  gemm_out_kernel<<<32 * 16, 256, 0, stream>>>(Ows, woT, bo, Y);
}